// Round 13
// baseline (214.158 us; speedup 1.0000x reference)
//
#include <hip/hip_runtime.h>
#include <hip/hip_bf16.h>

#define THREADS 256
#define GTHREADS 512   // gemm block size (8 waves)

typedef _Float16 half2_t __attribute__((ext_vector_type(2)));
typedef _Float16 half4_t __attribute__((ext_vector_type(4)));
typedef _Float16 half8_t __attribute__((ext_vector_type(8)));

__device__ inline float4 load4(const float* p) {
    return *reinterpret_cast<const float4*>(p);
}
__device__ inline float4 load4(const _Float16* p) {
    const half4_t t = *reinterpret_cast<const half4_t*>(p);
    return make_float4((float)t.x, (float)t.y, (float)t.z, (float)t.w);
}
__device__ inline void store4h(_Float16* p, float4 v) {
    half4_t t;
    t.x = (_Float16)v.x; t.y = (_Float16)v.y;
    t.z = (_Float16)v.z; t.w = (_Float16)v.w;
    *reinterpret_cast<half4_t*>(p) = t;
}

// ---------------------------------------------------------------------------
// Dual GEMM (layer 1) with CSR placement INTERLEAVED into every wave.
// Placement is at the random-write line-writeback wall (~1 TB/s, r6/r10);
// gemm1 hides under it. Plain csr stores (nontemporal regressed, r11).
// ---------------------------------------------------------------------------
template<typename Tin, int K, int R, int EPT>
__global__ __launch_bounds__(GTHREADS, 4) void gemm_place(
    const Tin* __restrict__ in, const float* __restrict__ Wl,
    const float* __restrict__ Wr, _Float16* __restrict__ outl,
    _Float16* __restrict__ outr, int nrows,
    const int* __restrict__ src, const int* __restrict__ dst,
    int* __restrict__ cursor, int* __restrict__ csr, int nedges)
{
    constexpr int KT = 64;                      // k-tile (LDS = 32 KB)
    __shared__ float4 sWl[KT * 16];             // [k][c4] : W[k][4c4..4c4+3]
    __shared__ float4 sWr[KT * 16];

    // ---- edge slice: coalesced loads issued up front ----
    int es[EPT], ed[EPT];
    const int e0 = blockIdx.x * (GTHREADS * EPT) + threadIdx.x;
    #pragma unroll
    for (int j = 0; j < EPT; ++j) {
        const int e = e0 + j * GTHREADS;
        const bool v = (e < nedges);
        es[j] = v ? src[e] : 0;
        ed[j] = v ? dst[e] : -1;                // -1 marks invalid
    }

    const int lane = threadIdx.x & 63;
    const int wid  = threadIdx.x >> 6;          // 0..7
    const int c4   = lane & 15;                 // col group
    const int rg   = lane >> 4;                 // 0..3 row-in-group
    const int wrow0 = blockIdx.x * (8 * 4 * R) + wid * (4 * R);

    int rr[R];
    #pragma unroll
    for (int r = 0; r < R; ++r) {
        const int row = wrow0 + r * 4 + rg;
        rr[r] = (row < nrows) ? row : (nrows - 1);   // clamp loads
    }

    float4 accl[R], accr[R];
    #pragma unroll
    for (int r = 0; r < R; ++r) {
        accl[r] = make_float4(0.f, 0.f, 0.f, 0.f);
        accr[r] = make_float4(0.f, 0.f, 0.f, 0.f);
    }

    auto do_tile = [&](int kt) {
        {   // stage W[kt .. kt+KT) (coalesced float4 copy)
            const float4* gWl = reinterpret_cast<const float4*>(Wl + kt * 64);
            const float4* gWr = reinterpret_cast<const float4*>(Wr + kt * 64);
            for (int i = threadIdx.x; i < KT * 16; i += GTHREADS) {
                sWl[i] = gWl[i];
                sWr[i] = gWr[i];
            }
        }
        __syncthreads();
        #pragma unroll 2
        for (int k4 = 0; k4 < KT / 4; ++k4) {
            float4 xv[R];
            #pragma unroll
            for (int r = 0; r < R; ++r)
                xv[r] = load4(in + (size_t)rr[r] * K + kt + k4 * 4);

            float4 wl[4], wr[4];
            #pragma unroll
            for (int j = 0; j < 4; ++j) {
                wl[j] = sWl[(k4 * 4 + j) * 16 + c4];
                wr[j] = sWr[(k4 * 4 + j) * 16 + c4];
            }
            #pragma unroll
            for (int r = 0; r < R; ++r) {
                const float x0 = xv[r].x, x1 = xv[r].y, x2 = xv[r].z, x3 = xv[r].w;
                accl[r].x = fmaf(x0, wl[0].x, accl[r].x);
                accl[r].y = fmaf(x0, wl[0].y, accl[r].y);
                accl[r].z = fmaf(x0, wl[0].z, accl[r].z);
                accl[r].w = fmaf(x0, wl[0].w, accl[r].w);
                accl[r].x = fmaf(x1, wl[1].x, accl[r].x);
                accl[r].y = fmaf(x1, wl[1].y, accl[r].y);
                accl[r].z = fmaf(x1, wl[1].z, accl[r].z);
                accl[r].w = fmaf(x1, wl[1].w, accl[r].w);
                accl[r].x = fmaf(x2, wl[2].x, accl[r].x);
                accl[r].y = fmaf(x2, wl[2].y, accl[r].y);
                accl[r].z = fmaf(x2, wl[2].z, accl[r].z);
                accl[r].w = fmaf(x2, wl[2].w, accl[r].w);
                accl[r].x = fmaf(x3, wl[3].x, accl[r].x);
                accl[r].y = fmaf(x3, wl[3].y, accl[r].y);
                accl[r].z = fmaf(x3, wl[3].z, accl[r].z);
                accl[r].w = fmaf(x3, wl[3].w, accl[r].w);

                accr[r].x = fmaf(x0, wr[0].x, accr[r].x);
                accr[r].y = fmaf(x0, wr[0].y, accr[r].y);
                accr[r].z = fmaf(x0, wr[0].z, accr[r].z);
                accr[r].w = fmaf(x0, wr[0].w, accr[r].w);
                accr[r].x = fmaf(x1, wr[1].x, accr[r].x);
                accr[r].y = fmaf(x1, wr[1].y, accr[r].y);
                accr[r].z = fmaf(x1, wr[1].z, accr[r].z);
                accr[r].w = fmaf(x1, wr[1].w, accr[r].w);
                accr[r].x = fmaf(x2, wr[2].x, accr[r].x);
                accr[r].y = fmaf(x2, wr[2].y, accr[r].y);
                accr[r].z = fmaf(x2, wr[2].z, accr[r].z);
                accr[r].w = fmaf(x2, wr[2].w, accr[r].w);
                accr[r].x = fmaf(x3, wr[3].x, accr[r].x);
                accr[r].y = fmaf(x3, wr[3].y, accr[r].y);
                accr[r].z = fmaf(x3, wr[3].z, accr[r].z);
                accr[r].w = fmaf(x3, wr[3].w, accr[r].w);
            }
        }
        __syncthreads();
    };

    // k-tile 0
    do_tile(0);

    // fire the placement atomics: independent, latency hides under the
    // remaining k-tiles / epilogue.
    int pos[EPT];
    #pragma unroll
    for (int j = 0; j < EPT; ++j)
        pos[j] = (ed[j] >= 0) ? atomicAdd(&cursor[ed[j]], 1) : 0;

    // remaining k-tiles
    for (int kt = KT; kt < K; kt += KT) do_tile(kt);

    // GEMM epilogue
    #pragma unroll
    for (int r = 0; r < R; ++r) {
        const int row = wrow0 + r * 4 + rg;
        if (row < nrows) {
            store4h(outl + (size_t)row * 64 + c4 * 4, accl[r]);
            store4h(outr + (size_t)row * 64 + c4 * 4, accr[r]);
        }
    }

    // placement stores (depend on atomic returns)
    #pragma unroll
    for (int j = 0; j < EPT; ++j)
        if (ed[j] >= 0) csr[pos[j]] = es[j];
}

// ---------------------------------------------------------------------------
// Fused aggregate1 + combine1(relu) + dual GEMM2.
// Block = 256 thr (4 waves) owns 64 nodes. Phase 1: each wave aggregates 16
// nodes (lane = channel gather of tmp rows), combines with bias+right+relu,
// writes the h-row to an LDS tile (fp16, 8 KB). Phase 2: dual GEMM on the
// LDS tile with the c4/rg lane map. h never touches global memory.
// OUTPUTS MUST NOT ALIAS y (r12 bug: outl==tmp raced with the gather).
// LDS = 32 KB (W2) + 8 KB (tile) -> 4 blocks/CU.
// ---------------------------------------------------------------------------
__global__ __launch_bounds__(THREADS, 4) void agg_gemm(
    const _Float16* __restrict__ y,       // tmp = x@W1l  [N,64]
    const int* __restrict__ csr, const int* __restrict__ offs,
    const int* __restrict__ deg,
    const _Float16* __restrict__ right,   // h = x@W1r
    const float* __restrict__ bias,       // b1
    const float* __restrict__ W2l, const float* __restrict__ W2r,
    _Float16* __restrict__ outl,          // msg2 = h@W2l  (distinct buffer!)
    _Float16* __restrict__ outr,          // z    = h@W2r
    int n)
{
    __shared__ float4 sWl[64 * 16];       // 16 KB  [k][c4]
    __shared__ float4 sWr[64 * 16];       // 16 KB
    __shared__ _Float16 xt[64 * 64];      // 8 KB   h-tile

    {   // stage W2 (coalesced float4 copy)
        const float4* gWl = reinterpret_cast<const float4*>(W2l);
        const float4* gWr = reinterpret_cast<const float4*>(W2r);
        for (int i = threadIdx.x; i < 64 * 16; i += THREADS) {
            sWl[i] = gWl[i];
            sWr[i] = gWr[i];
        }
    }

    const int lane = threadIdx.x & 63;
    const int wv   = threadIdx.x >> 6;    // 0..3

    // ---- phase 1: aggregate + combine 16 nodes per wave ----
    for (int j = 0; j < 16; ++j) {
        const int local_n = wv * 16 + j;
        const int node = blockIdx.x * 64 + local_n;
        float v = 0.f;
        if (node < n) {
            const int start = __builtin_amdgcn_readfirstlane(offs[node]);
            const int d     = __builtin_amdgcn_readfirstlane(deg[node]);
            float acc = 0.f;
            int i = 0;
            for (; i + 8 <= d; i += 8) {
                int ss[8];
                #pragma unroll
                for (int t = 0; t < 8; ++t)
                    ss[t] = __builtin_amdgcn_readfirstlane(csr[start + i + t]);
                float a[8];
                #pragma unroll
                for (int t = 0; t < 8; ++t)
                    a[t] = (float)y[(size_t)ss[t] * 64 + lane];
                #pragma unroll
                for (int t = 0; t < 8; ++t)
                    acc += a[t];
            }
            for (; i < d; ++i) {
                const int s = __builtin_amdgcn_readfirstlane(csr[start + i]);
                acc += (float)y[(size_t)s * 64 + lane];
            }
            const float inv = 1.0f / (float)(d > 0 ? d : 1);
            v = fmaf(acc, inv, bias[lane] + (float)right[(size_t)node * 64 + lane]);
            v = fmaxf(v, 0.f);                 // relu
        }
        xt[local_n * 64 + lane] = (_Float16)v;
    }
    __syncthreads();

    // ---- phase 2: dual GEMM on the 64x64 LDS tile ----
    const int c4 = lane & 15;
    const int rg = lane >> 4;
    float4 accl[4], accr[4];
    #pragma unroll
    for (int r = 0; r < 4; ++r) {
        accl[r] = make_float4(0.f, 0.f, 0.f, 0.f);
        accr[r] = make_float4(0.f, 0.f, 0.f, 0.f);
    }

    #pragma unroll 2
    for (int k4 = 0; k4 < 16; ++k4) {
        float4 xv[4];
        #pragma unroll
        for (int r = 0; r < 4; ++r) {
            const int lrow = wv * 16 + r * 4 + rg;
            const half4_t hx = *reinterpret_cast<const half4_t*>(&xt[lrow * 64 + k4 * 4]);
            xv[r] = make_float4((float)hx.x, (float)hx.y, (float)hx.z, (float)hx.w);
        }
        float4 wl[4], wr[4];
        #pragma unroll
        for (int j = 0; j < 4; ++j) {
            wl[j] = sWl[(k4 * 4 + j) * 16 + c4];
            wr[j] = sWr[(k4 * 4 + j) * 16 + c4];
        }
        #pragma unroll
        for (int r = 0; r < 4; ++r) {
            const float x0 = xv[r].x, x1 = xv[r].y, x2 = xv[r].z, x3 = xv[r].w;
            accl[r].x = fmaf(x0, wl[0].x, accl[r].x);
            accl[r].y = fmaf(x0, wl[0].y, accl[r].y);
            accl[r].z = fmaf(x0, wl[0].z, accl[r].z);
            accl[r].w = fmaf(x0, wl[0].w, accl[r].w);
            accl[r].x = fmaf(x1, wl[1].x, accl[r].x);
            accl[r].y = fmaf(x1, wl[1].y, accl[r].y);
            accl[r].z = fmaf(x1, wl[1].z, accl[r].z);
            accl[r].w = fmaf(x1, wl[1].w, accl[r].w);
            accl[r].x = fmaf(x2, wl[2].x, accl[r].x);
            accl[r].y = fmaf(x2, wl[2].y, accl[r].y);
            accl[r].z = fmaf(x2, wl[2].z, accl[r].z);
            accl[r].w = fmaf(x2, wl[2].w, accl[r].w);
            accl[r].x = fmaf(x3, wl[3].x, accl[r].x);
            accl[r].y = fmaf(x3, wl[3].y, accl[r].y);
            accl[r].z = fmaf(x3, wl[3].z, accl[r].z);
            accl[r].w = fmaf(x3, wl[3].w, accl[r].w);

            accr[r].x = fmaf(x0, wr[0].x, accr[r].x);
            accr[r].y = fmaf(x0, wr[0].y, accr[r].y);
            accr[r].z = fmaf(x0, wr[0].z, accr[r].z);
            accr[r].w = fmaf(x0, wr[0].w, accr[r].w);
            accr[r].x = fmaf(x1, wr[1].x, accr[r].x);
            accr[r].y = fmaf(x1, wr[1].y, accr[r].y);
            accr[r].z = fmaf(x1, wr[1].z, accr[r].z);
            accr[r].w = fmaf(x1, wr[1].w, accr[r].w);
            accr[r].x = fmaf(x2, wr[2].x, accr[r].x);
            accr[r].y = fmaf(x2, wr[2].y, accr[r].y);
            accr[r].z = fmaf(x2, wr[2].z, accr[r].z);
            accr[r].w = fmaf(x2, wr[2].w, accr[r].w);
            accr[r].x = fmaf(x3, wr[3].x, accr[r].x);
            accr[r].y = fmaf(x3, wr[3].y, accr[r].y);
            accr[r].z = fmaf(x3, wr[3].z, accr[r].z);
            accr[r].w = fmaf(x3, wr[3].w, accr[r].w);
        }
    }

    #pragma unroll
    for (int r = 0; r < 4; ++r) {
        const int row = blockIdx.x * 64 + wv * 16 + r * 4 + rg;
        if (row < n) {
            store4h(outl + (size_t)row * 64 + c4 * 4, accl[r]);
            store4h(outr + (size_t)row * 64 + c4 * 4, accr[r]);
        }
    }
}

// ---------------------------------------------------------------------------
// CSR build: histogram of dst, exclusive scan (2 dispatches).
// ---------------------------------------------------------------------------
__global__ __launch_bounds__(THREADS) void hist_kernel(
    const int* __restrict__ dst, int* __restrict__ deg, int nedges)
{
    const int e = blockIdx.x * THREADS + threadIdx.x;
    if (e < nedges) atomicAdd(&deg[dst[e]], 1);
}

__global__ __launch_bounds__(THREADS) void scan_reduce(
    const int* __restrict__ deg, int* __restrict__ bsum, int n)
{
    __shared__ int s[THREADS];
    const int i = blockIdx.x * THREADS + threadIdx.x;
    s[threadIdx.x] = (i < n) ? deg[i] : 0;
    __syncthreads();
    for (int off = THREADS / 2; off > 0; off >>= 1) {
        if (threadIdx.x < off) s[threadIdx.x] += s[threadIdx.x + off];
        __syncthreads();
    }
    if (threadIdx.x == 0) bsum[blockIdx.x] = s[0];
}

// scan_apply with inline block-prefix (saves the scan_top dispatch).
__global__ __launch_bounds__(THREADS) void scan_apply(
    const int* __restrict__ deg, const int* __restrict__ bsum,
    int* __restrict__ offs, int* __restrict__ cursor, int n)
{
    __shared__ int s[THREADS];
    __shared__ int base;
    const int t = threadIdx.x;

    int pb = 0;
    for (int j = t; j < (int)blockIdx.x; j += THREADS) pb += bsum[j];
    s[t] = pb;
    __syncthreads();
    for (int off = THREADS / 2; off > 0; off >>= 1) {
        if (t < off) s[t] += s[t + off];
        __syncthreads();
    }
    if (t == 0) base = s[0];
    __syncthreads();

    const int i = blockIdx.x * THREADS + t;
    const int v = (i < n) ? deg[i] : 0;
    s[t] = v;
    __syncthreads();
    for (int off = 1; off < THREADS; off <<= 1) {
        const int a = (t >= off) ? s[t - off] : 0;
        __syncthreads();
        s[t] += a;
        __syncthreads();
    }
    if (i < n) {
        const int ex = base + s[t] - v;
        offs[i] = ex;
        cursor[i] = ex;
    }
}

// ---------------------------------------------------------------------------
// Fused mean-aggregate + combine, layer 2 (fp16 payload, fp32 accum).
// ---------------------------------------------------------------------------
__global__ __launch_bounds__(THREADS) void aggregate_fused(
    const _Float16* __restrict__ y, const int* __restrict__ csr,
    const int* __restrict__ offs, const int* __restrict__ deg,
    const _Float16* __restrict__ right, const float* __restrict__ bias,
    _Float16* __restrict__ out, int n, int relu)
{
    int node = blockIdx.x * (THREADS / 64) + (threadIdx.x >> 6);
    if (node >= n) return;
    node = __builtin_amdgcn_readfirstlane(node);   // wave-uniform
    const int lane = threadIdx.x & 63;
    const int start = __builtin_amdgcn_readfirstlane(offs[node]);
    const int d     = __builtin_amdgcn_readfirstlane(deg[node]);

    float acc = 0.f;
    int i = 0;
    for (; i + 8 <= d; i += 8) {
        int ss[8];
        #pragma unroll
        for (int j = 0; j < 8; ++j)
            ss[j] = __builtin_amdgcn_readfirstlane(csr[start + i + j]);
        float a[8];
        #pragma unroll
        for (int j = 0; j < 8; ++j)
            a[j] = (float)y[(size_t)ss[j] * 64 + lane];
        #pragma unroll
        for (int j = 0; j < 8; ++j)
            acc += a[j];
    }
    for (; i < d; ++i) {
        const int s = __builtin_amdgcn_readfirstlane(csr[start + i]);
        acc += (float)y[(size_t)s * 64 + lane];
    }

    const float inv = 1.0f / (float)(d > 0 ? d : 1);
    float v = fmaf(acc, inv, bias[lane] + (float)right[(size_t)node * 64 + lane]);
    if (relu) v = fmaxf(v, 0.f);
    out[(size_t)node * 64 + lane] = (_Float16)v;
}

// ---------------------------------------------------------------------------
// out[e] = dot(z[src[e]], z[dst[e]]) over 64 ch (fp16 z, fp32 accum);
// 8 lanes/edge, 16B loads, v_dot2_f32_f16 where available.
// ---------------------------------------------------------------------------
__global__ __launch_bounds__(THREADS) void score_kernel(
    const _Float16* __restrict__ z, const int* __restrict__ src,
    const int* __restrict__ dst, float* __restrict__ out, int nedges)
{
    const int gid = blockIdx.x * THREADS + threadIdx.x;
    const int e = gid >> 3;
    const int g = gid & 7;
    if (e >= nedges) return;
    const int s = src[e];
    const int d = dst[e];
    const half8_t a = *reinterpret_cast<const half8_t*>(z + (size_t)s * 64 + g * 8);
    const half8_t b = *reinterpret_cast<const half8_t*>(z + (size_t)d * 64 + g * 8);
    float p = 0.f;
#if __has_builtin(__builtin_amdgcn_fdot2)
    #pragma unroll
    for (int j = 0; j < 4; ++j) {
        half2_t a2, b2;
        a2.x = a[2 * j]; a2.y = a[2 * j + 1];
        b2.x = b[2 * j]; b2.y = b[2 * j + 1];
        p = __builtin_amdgcn_fdot2(a2, b2, p, false);
    }
#else
    #pragma unroll
    for (int j = 0; j < 8; ++j)
        p = fmaf((float)a[j], (float)b[j], p);
#endif
    p += __shfl_down(p, 4, 8);
    p += __shfl_down(p, 2, 8);
    p += __shfl_down(p, 1, 8);
    if (g == 0) out[e] = p;
}

extern "C" void kernel_launch(void* const* d_in, const int* in_sizes, int n_in,
                              void* d_out, int out_size, void* d_ws, size_t ws_size,
                              hipStream_t stream)
{
    const float* x   = (const float*)d_in[0];   // [N, 128]
    const int*   ei  = (const int*)  d_in[1];   // [2, E]
    const float* W1l = (const float*)d_in[2];   // [128, 64]
    const float* b1  = (const float*)d_in[3];   // [64]
    const float* W1r = (const float*)d_in[4];   // [128, 64]
    const float* W2l = (const float*)d_in[5];   // [64, 64]
    const float* b2  = (const float*)d_in[6];   // [64]
    const float* W2r = (const float*)d_in[7];   // [64, 64]
    float* out = (float*)d_out;

    const int N = in_sizes[0] / 128;            // 50000
    const int E = in_sizes[1] / 2;              // 800000
    const int* src = ei;
    const int* dst = ei + E;

    const size_t N64 = (size_t)N * 64;
    _Float16* tmp  = (_Float16*)d_ws;           // [N,64]  x@W1l (layer-1 msgs)
    _Float16* h    = tmp + N64;                 // [N,64]  x@W1r (right term)
    _Float16* z    = h + N64;                   // [N,64]  layer-2 output
    _Float16* msg2 = z + N64;                   // [N,64]  h@W2l (layer-2 msgs)
    int* deg    = (int*)(msg2 + N64);           // [N]
    int* offs   = deg + N;                      // [N]
    int* cursor = offs + N;                     // [N]
    int* csr    = cursor + N;                   // [E]
    int* bsum   = csr + E;                      // [ceil(N/256)]

    constexpr int R = 2;                        // row-iters per lane
    constexpr int EPT = 2;                      // edges per thread (placement)
    const int rows_per_block = 8 * 4 * R;       // 64
    const int nb          = (N + THREADS - 1) / THREADS;
    const int edge_blocks = (E + THREADS - 1) / THREADS;
    const int gemm_rows_blocks = (N + rows_per_block - 1) / rows_per_block; // 782
    const int edge_cover_blocks = (E + GTHREADS * EPT - 1) / (GTHREADS * EPT);
    const int gemm_blocks = gemm_rows_blocks > edge_cover_blocks
                          ? gemm_rows_blocks : edge_cover_blocks;           // 782
    const int aggm_blocks = (N + 63) / 64;                     // 782
    const int aggr_blocks = (N + 3) / 4;
    const int scor_blocks = (E * 8 + THREADS - 1) / THREADS;

    // ---- CSR prefix (histogram + scan) ----
    hipMemsetAsync(deg, 0, (size_t)N * sizeof(int), stream);
    hist_kernel<<<edge_blocks, THREADS, 0, stream>>>(dst, deg, E);
    scan_reduce<<<nb, THREADS, 0, stream>>>(deg, bsum, N);
    scan_apply<<<nb, THREADS, 0, stream>>>(deg, bsum, offs, cursor, N);

    // ---- layer 1 GEMM with placement interleaved ----
    gemm_place<float, 128, R, EPT><<<gemm_blocks, GTHREADS, 0, stream>>>(
        x, W1l, W1r, tmp, h, N, src, dst, cursor, csr, E);

    // ---- aggregate1 + combine1 + GEMM2 fused (h stays on-chip) ----
    agg_gemm<<<aggm_blocks, THREADS, 0, stream>>>(
        tmp, csr, offs, deg, h, b1, W2l, W2r, msg2, z, N);

    // ---- layer 2 aggregate + combine ----
    aggregate_fused<<<aggr_blocks, THREADS, 0, stream>>>(msg2, csr, offs, deg, z, b2, z, N, 0);

    // ---- decode ----
    score_kernel<<<scor_blocks, THREADS, 0, stream>>>(z, src, dst, out, E);
}

// Round 14
// 199.708 us; speedup vs baseline: 1.0724x; 1.0724x over previous
//
#include <hip/hip_runtime.h>
#include <hip/hip_bf16.h>

#define THREADS 256
#define GTHREADS 512   // gemm block size (8 waves)

typedef _Float16 half2_t __attribute__((ext_vector_type(2)));
typedef _Float16 half4_t __attribute__((ext_vector_type(4)));
typedef _Float16 half8_t __attribute__((ext_vector_type(8)));

__device__ inline float4 load4(const float* p) {
    return *reinterpret_cast<const float4*>(p);
}
__device__ inline float4 load4(const _Float16* p) {
    const half4_t t = *reinterpret_cast<const half4_t*>(p);
    return make_float4((float)t.x, (float)t.y, (float)t.z, (float)t.w);
}
__device__ inline void store4h(_Float16* p, float4 v) {
    half4_t t;
    t.x = (_Float16)v.x; t.y = (_Float16)v.y;
    t.z = (_Float16)v.z; t.w = (_Float16)v.w;
    *reinterpret_cast<half4_t*>(p) = t;
}

// ---------------------------------------------------------------------------
// Dual GEMM (layer 1) with CSR placement INTERLEAVED into every wave.
// Placement is at the random-write line-writeback wall (~1 TB/s, r6/r10);
// gemm1 hides under it. Plain csr stores (nontemporal regressed, r11).
// ---------------------------------------------------------------------------
template<typename Tin, int K, int R, int EPT>
__global__ __launch_bounds__(GTHREADS, 4) void gemm_place(
    const Tin* __restrict__ in, const float* __restrict__ Wl,
    const float* __restrict__ Wr, _Float16* __restrict__ outl,
    _Float16* __restrict__ outr, int nrows,
    const int* __restrict__ src, const int* __restrict__ dst,
    int* __restrict__ cursor, int* __restrict__ csr, int nedges)
{
    constexpr int KT = 64;                      // k-tile (LDS = 32 KB)
    __shared__ float4 sWl[KT * 16];             // [k][c4] : W[k][4c4..4c4+3]
    __shared__ float4 sWr[KT * 16];

    // ---- edge slice: coalesced loads issued up front ----
    int es[EPT], ed[EPT];
    const int e0 = blockIdx.x * (GTHREADS * EPT) + threadIdx.x;
    #pragma unroll
    for (int j = 0; j < EPT; ++j) {
        const int e = e0 + j * GTHREADS;
        const bool v = (e < nedges);
        es[j] = v ? src[e] : 0;
        ed[j] = v ? dst[e] : -1;                // -1 marks invalid
    }

    const int lane = threadIdx.x & 63;
    const int wid  = threadIdx.x >> 6;          // 0..7
    const int c4   = lane & 15;                 // col group
    const int rg   = lane >> 4;                 // 0..3 row-in-group
    const int wrow0 = blockIdx.x * (8 * 4 * R) + wid * (4 * R);

    int rr[R];
    #pragma unroll
    for (int r = 0; r < R; ++r) {
        const int row = wrow0 + r * 4 + rg;
        rr[r] = (row < nrows) ? row : (nrows - 1);   // clamp loads
    }

    float4 accl[R], accr[R];
    #pragma unroll
    for (int r = 0; r < R; ++r) {
        accl[r] = make_float4(0.f, 0.f, 0.f, 0.f);
        accr[r] = make_float4(0.f, 0.f, 0.f, 0.f);
    }

    auto do_tile = [&](int kt) {
        {   // stage W[kt .. kt+KT) (coalesced float4 copy)
            const float4* gWl = reinterpret_cast<const float4*>(Wl + kt * 64);
            const float4* gWr = reinterpret_cast<const float4*>(Wr + kt * 64);
            for (int i = threadIdx.x; i < KT * 16; i += GTHREADS) {
                sWl[i] = gWl[i];
                sWr[i] = gWr[i];
            }
        }
        __syncthreads();
        #pragma unroll 2
        for (int k4 = 0; k4 < KT / 4; ++k4) {
            float4 xv[R];
            #pragma unroll
            for (int r = 0; r < R; ++r)
                xv[r] = load4(in + (size_t)rr[r] * K + kt + k4 * 4);

            float4 wl[4], wr[4];
            #pragma unroll
            for (int j = 0; j < 4; ++j) {
                wl[j] = sWl[(k4 * 4 + j) * 16 + c4];
                wr[j] = sWr[(k4 * 4 + j) * 16 + c4];
            }
            #pragma unroll
            for (int r = 0; r < R; ++r) {
                const float x0 = xv[r].x, x1 = xv[r].y, x2 = xv[r].z, x3 = xv[r].w;
                accl[r].x = fmaf(x0, wl[0].x, accl[r].x);
                accl[r].y = fmaf(x0, wl[0].y, accl[r].y);
                accl[r].z = fmaf(x0, wl[0].z, accl[r].z);
                accl[r].w = fmaf(x0, wl[0].w, accl[r].w);
                accl[r].x = fmaf(x1, wl[1].x, accl[r].x);
                accl[r].y = fmaf(x1, wl[1].y, accl[r].y);
                accl[r].z = fmaf(x1, wl[1].z, accl[r].z);
                accl[r].w = fmaf(x1, wl[1].w, accl[r].w);
                accl[r].x = fmaf(x2, wl[2].x, accl[r].x);
                accl[r].y = fmaf(x2, wl[2].y, accl[r].y);
                accl[r].z = fmaf(x2, wl[2].z, accl[r].z);
                accl[r].w = fmaf(x2, wl[2].w, accl[r].w);
                accl[r].x = fmaf(x3, wl[3].x, accl[r].x);
                accl[r].y = fmaf(x3, wl[3].y, accl[r].y);
                accl[r].z = fmaf(x3, wl[3].z, accl[r].z);
                accl[r].w = fmaf(x3, wl[3].w, accl[r].w);

                accr[r].x = fmaf(x0, wr[0].x, accr[r].x);
                accr[r].y = fmaf(x0, wr[0].y, accr[r].y);
                accr[r].z = fmaf(x0, wr[0].z, accr[r].z);
                accr[r].w = fmaf(x0, wr[0].w, accr[r].w);
                accr[r].x = fmaf(x1, wr[1].x, accr[r].x);
                accr[r].y = fmaf(x1, wr[1].y, accr[r].y);
                accr[r].z = fmaf(x1, wr[1].z, accr[r].z);
                accr[r].w = fmaf(x1, wr[1].w, accr[r].w);
                accr[r].x = fmaf(x2, wr[2].x, accr[r].x);
                accr[r].y = fmaf(x2, wr[2].y, accr[r].y);
                accr[r].z = fmaf(x2, wr[2].z, accr[r].z);
                accr[r].w = fmaf(x2, wr[2].w, accr[r].w);
                accr[r].x = fmaf(x3, wr[3].x, accr[r].x);
                accr[r].y = fmaf(x3, wr[3].y, accr[r].y);
                accr[r].z = fmaf(x3, wr[3].z, accr[r].z);
                accr[r].w = fmaf(x3, wr[3].w, accr[r].w);
            }
        }
        __syncthreads();
    };

    // k-tile 0
    do_tile(0);

    // fire the placement atomics: independent, latency hides under the
    // remaining k-tiles / epilogue.
    int pos[EPT];
    #pragma unroll
    for (int j = 0; j < EPT; ++j)
        pos[j] = (ed[j] >= 0) ? atomicAdd(&cursor[ed[j]], 1) : 0;

    // remaining k-tiles
    for (int kt = KT; kt < K; kt += KT) do_tile(kt);

    // GEMM epilogue
    #pragma unroll
    for (int r = 0; r < R; ++r) {
        const int row = wrow0 + r * 4 + rg;
        if (row < nrows) {
            store4h(outl + (size_t)row * 64 + c4 * 4, accl[r]);
            store4h(outr + (size_t)row * 64 + c4 * 4, accr[r]);
        }
    }

    // placement stores (depend on atomic returns)
    #pragma unroll
    for (int j = 0; j < EPT; ++j)
        if (ed[j] >= 0) csr[pos[j]] = es[j];
}

// ---------------------------------------------------------------------------
// Fused aggregate1 + combine1(relu) + dual GEMM2 — OCCUPANCY-FIXED (r13 ran
// at 12 waves/CU from 40 KB LDS; gather phase needs ~32). Now: 256 thr, 32
// nodes/block (8/wave), W2 staged as fp16 (8+8 KB; |W2|<=0.125 so fp16 err
// negligible), tile padded 32x68 halfs (4.25 KB) -> 20.25 KB LDS -> 7
// blocks/CU cap, grid 1563 ~ 6.1/CU ~ 24+ waves/CU for the gather.
// Outputs must not alias y (r12 race).
// ---------------------------------------------------------------------------
__global__ __launch_bounds__(THREADS, 6) void agg_gemm(
    const _Float16* __restrict__ y,       // tmp = x@W1l  [N,64]
    const int* __restrict__ csr, const int* __restrict__ offs,
    const int* __restrict__ deg,
    const _Float16* __restrict__ right,   // h = x@W1r
    const float* __restrict__ bias,       // b1
    const float* __restrict__ W2l, const float* __restrict__ W2r,
    _Float16* __restrict__ outl,          // msg2 = h@W2l
    _Float16* __restrict__ outr,          // z0   = h@W2r
    int n)
{
    __shared__ _Float16 sWl[64 * 64];     // 8 KB  fp16 [k][c]
    __shared__ _Float16 sWr[64 * 64];     // 8 KB
    __shared__ _Float16 xt[32 * 68];      // 4.25 KB  h-tile (padded rows)

    {   // stage W2 fp32 -> fp16 (coalesced)
        for (int i = threadIdx.x; i < 64 * 64; i += THREADS) {
            sWl[i] = (_Float16)W2l[i];
            sWr[i] = (_Float16)W2r[i];
        }
    }

    const int lane = threadIdx.x & 63;
    const int wv   = threadIdx.x >> 6;    // 0..3

    // ---- phase 1: aggregate + combine 8 nodes per wave ----
    for (int j = 0; j < 8; ++j) {
        const int local_n = wv * 8 + j;
        const int node = blockIdx.x * 32 + local_n;
        float v = 0.f;
        if (node < n) {
            const int start = __builtin_amdgcn_readfirstlane(offs[node]);
            const int d     = __builtin_amdgcn_readfirstlane(deg[node]);
            float acc = 0.f;
            int i = 0;
            for (; i + 8 <= d; i += 8) {
                int ss[8];
                #pragma unroll
                for (int t = 0; t < 8; ++t)
                    ss[t] = __builtin_amdgcn_readfirstlane(csr[start + i + t]);
                float a[8];
                #pragma unroll
                for (int t = 0; t < 8; ++t)
                    a[t] = (float)y[(size_t)ss[t] * 64 + lane];
                #pragma unroll
                for (int t = 0; t < 8; ++t)
                    acc += a[t];
            }
            for (; i < d; ++i) {
                const int s = __builtin_amdgcn_readfirstlane(csr[start + i]);
                acc += (float)y[(size_t)s * 64 + lane];
            }
            const float inv = 1.0f / (float)(d > 0 ? d : 1);
            v = fmaf(acc, inv, bias[lane] + (float)right[(size_t)node * 64 + lane]);
            v = fmaxf(v, 0.f);                 // relu
        }
        xt[local_n * 68 + lane] = (_Float16)v;
    }
    __syncthreads();

    // ---- phase 2: dual GEMM on the 32x64 LDS tile (R=2 rows/lane) ----
    const int c4 = lane & 15;
    const int rg = lane >> 4;
    float4 accl[2], accr[2];
    #pragma unroll
    for (int r = 0; r < 2; ++r) {
        accl[r] = make_float4(0.f, 0.f, 0.f, 0.f);
        accr[r] = make_float4(0.f, 0.f, 0.f, 0.f);
    }

    #pragma unroll 2
    for (int k4 = 0; k4 < 16; ++k4) {
        float4 xv[2];
        #pragma unroll
        for (int r = 0; r < 2; ++r) {
            const int lrow = wv * 8 + r * 4 + rg;
            const half4_t hx = *reinterpret_cast<const half4_t*>(&xt[lrow * 68 + k4 * 4]);
            xv[r] = make_float4((float)hx.x, (float)hx.y, (float)hx.z, (float)hx.w);
        }
        float4 wl[4], wr[4];
        #pragma unroll
        for (int j = 0; j < 4; ++j) {
            const half4_t hl = *reinterpret_cast<const half4_t*>(&sWl[(k4 * 4 + j) * 64 + c4 * 4]);
            const half4_t hr = *reinterpret_cast<const half4_t*>(&sWr[(k4 * 4 + j) * 64 + c4 * 4]);
            wl[j] = make_float4((float)hl.x, (float)hl.y, (float)hl.z, (float)hl.w);
            wr[j] = make_float4((float)hr.x, (float)hr.y, (float)hr.z, (float)hr.w);
        }
        #pragma unroll
        for (int r = 0; r < 2; ++r) {
            const float x0 = xv[r].x, x1 = xv[r].y, x2 = xv[r].z, x3 = xv[r].w;
            accl[r].x = fmaf(x0, wl[0].x, accl[r].x);
            accl[r].y = fmaf(x0, wl[0].y, accl[r].y);
            accl[r].z = fmaf(x0, wl[0].z, accl[r].z);
            accl[r].w = fmaf(x0, wl[0].w, accl[r].w);
            accl[r].x = fmaf(x1, wl[1].x, accl[r].x);
            accl[r].y = fmaf(x1, wl[1].y, accl[r].y);
            accl[r].z = fmaf(x1, wl[1].z, accl[r].z);
            accl[r].w = fmaf(x1, wl[1].w, accl[r].w);
            accl[r].x = fmaf(x2, wl[2].x, accl[r].x);
            accl[r].y = fmaf(x2, wl[2].y, accl[r].y);
            accl[r].z = fmaf(x2, wl[2].z, accl[r].z);
            accl[r].w = fmaf(x2, wl[2].w, accl[r].w);
            accl[r].x = fmaf(x3, wl[3].x, accl[r].x);
            accl[r].y = fmaf(x3, wl[3].y, accl[r].y);
            accl[r].z = fmaf(x3, wl[3].z, accl[r].z);
            accl[r].w = fmaf(x3, wl[3].w, accl[r].w);

            accr[r].x = fmaf(x0, wr[0].x, accr[r].x);
            accr[r].y = fmaf(x0, wr[0].y, accr[r].y);
            accr[r].z = fmaf(x0, wr[0].z, accr[r].z);
            accr[r].w = fmaf(x0, wr[0].w, accr[r].w);
            accr[r].x = fmaf(x1, wr[1].x, accr[r].x);
            accr[r].y = fmaf(x1, wr[1].y, accr[r].y);
            accr[r].z = fmaf(x1, wr[1].z, accr[r].z);
            accr[r].w = fmaf(x1, wr[1].w, accr[r].w);
            accr[r].x = fmaf(x2, wr[2].x, accr[r].x);
            accr[r].y = fmaf(x2, wr[2].y, accr[r].y);
            accr[r].z = fmaf(x2, wr[2].z, accr[r].z);
            accr[r].w = fmaf(x2, wr[2].w, accr[r].w);
            accr[r].x = fmaf(x3, wr[3].x, accr[r].x);
            accr[r].y = fmaf(x3, wr[3].y, accr[r].y);
            accr[r].z = fmaf(x3, wr[3].z, accr[r].z);
            accr[r].w = fmaf(x3, wr[3].w, accr[r].w);
        }
    }

    #pragma unroll
    for (int r = 0; r < 2; ++r) {
        const int row = blockIdx.x * 32 + wv * 8 + r * 4 + rg;
        if (row < n) {
            store4h(outl + (size_t)row * 64 + c4 * 4, accl[r]);
            store4h(outr + (size_t)row * 64 + c4 * 4, accr[r]);
        }
    }
}

// ---------------------------------------------------------------------------
// CSR build: histogram of dst, exclusive scan (2 dispatches).
// ---------------------------------------------------------------------------
__global__ __launch_bounds__(THREADS) void hist_kernel(
    const int* __restrict__ dst, int* __restrict__ deg, int nedges)
{
    const int e = blockIdx.x * THREADS + threadIdx.x;
    if (e < nedges) atomicAdd(&deg[dst[e]], 1);
}

__global__ __launch_bounds__(THREADS) void scan_reduce(
    const int* __restrict__ deg, int* __restrict__ bsum, int n)
{
    __shared__ int s[THREADS];
    const int i = blockIdx.x * THREADS + threadIdx.x;
    s[threadIdx.x] = (i < n) ? deg[i] : 0;
    __syncthreads();
    for (int off = THREADS / 2; off > 0; off >>= 1) {
        if (threadIdx.x < off) s[threadIdx.x] += s[threadIdx.x + off];
        __syncthreads();
    }
    if (threadIdx.x == 0) bsum[blockIdx.x] = s[0];
}

// scan_apply with inline block-prefix (saves the scan_top dispatch).
__global__ __launch_bounds__(THREADS) void scan_apply(
    const int* __restrict__ deg, const int* __restrict__ bsum,
    int* __restrict__ offs, int* __restrict__ cursor, int n)
{
    __shared__ int s[THREADS];
    __shared__ int base;
    const int t = threadIdx.x;

    int pb = 0;
    for (int j = t; j < (int)blockIdx.x; j += THREADS) pb += bsum[j];
    s[t] = pb;
    __syncthreads();
    for (int off = THREADS / 2; off > 0; off >>= 1) {
        if (t < off) s[t] += s[t + off];
        __syncthreads();
    }
    if (t == 0) base = s[0];
    __syncthreads();

    const int i = blockIdx.x * THREADS + t;
    const int v = (i < n) ? deg[i] : 0;
    s[t] = v;
    __syncthreads();
    for (int off = 1; off < THREADS; off <<= 1) {
        const int a = (t >= off) ? s[t - off] : 0;
        __syncthreads();
        s[t] += a;
        __syncthreads();
    }
    if (i < n) {
        const int ex = base + s[t] - v;
        offs[i] = ex;
        cursor[i] = ex;
    }
}

// ---------------------------------------------------------------------------
// Fused mean-aggregate + combine, layer 2 (fp16 payload, fp32 accum).
// ---------------------------------------------------------------------------
__global__ __launch_bounds__(THREADS) void aggregate_fused(
    const _Float16* __restrict__ y, const int* __restrict__ csr,
    const int* __restrict__ offs, const int* __restrict__ deg,
    const _Float16* __restrict__ right, const float* __restrict__ bias,
    _Float16* __restrict__ out, int n, int relu)
{
    int node = blockIdx.x * (THREADS / 64) + (threadIdx.x >> 6);
    if (node >= n) return;
    node = __builtin_amdgcn_readfirstlane(node);   // wave-uniform
    const int lane = threadIdx.x & 63;
    const int start = __builtin_amdgcn_readfirstlane(offs[node]);
    const int d     = __builtin_amdgcn_readfirstlane(deg[node]);

    float acc = 0.f;
    int i = 0;
    for (; i + 8 <= d; i += 8) {
        int ss[8];
        #pragma unroll
        for (int j = 0; j < 8; ++j)
            ss[j] = __builtin_amdgcn_readfirstlane(csr[start + i + j]);
        float a[8];
        #pragma unroll
        for (int j = 0; j < 8; ++j)
            a[j] = (float)y[(size_t)ss[j] * 64 + lane];
        #pragma unroll
        for (int j = 0; j < 8; ++j)
            acc += a[j];
    }
    for (; i < d; ++i) {
        const int s = __builtin_amdgcn_readfirstlane(csr[start + i]);
        acc += (float)y[(size_t)s * 64 + lane];
    }

    const float inv = 1.0f / (float)(d > 0 ? d : 1);
    float v = fmaf(acc, inv, bias[lane] + (float)right[(size_t)node * 64 + lane]);
    if (relu) v = fmaxf(v, 0.f);
    out[(size_t)node * 64 + lane] = (_Float16)v;
}

// ---------------------------------------------------------------------------
// out[e] = dot(z[src[e]], z[dst[e]]) over 64 ch (fp16 z, fp32 accum);
// 8 lanes/edge, 16B loads, v_dot2_f32_f16 where available.
// ---------------------------------------------------------------------------
__global__ __launch_bounds__(THREADS) void score_kernel(
    const _Float16* __restrict__ z, const int* __restrict__ src,
    const int* __restrict__ dst, float* __restrict__ out, int nedges)
{
    const int gid = blockIdx.x * THREADS + threadIdx.x;
    const int e = gid >> 3;
    const int g = gid & 7;
    if (e >= nedges) return;
    const int s = src[e];
    const int d = dst[e];
    const half8_t a = *reinterpret_cast<const half8_t*>(z + (size_t)s * 64 + g * 8);
    const half8_t b = *reinterpret_cast<const half8_t*>(z + (size_t)d * 64 + g * 8);
    float p = 0.f;
#if __has_builtin(__builtin_amdgcn_fdot2)
    #pragma unroll
    for (int j = 0; j < 4; ++j) {
        half2_t a2, b2;
        a2.x = a[2 * j]; a2.y = a[2 * j + 1];
        b2.x = b[2 * j]; b2.y = b[2 * j + 1];
        p = __builtin_amdgcn_fdot2(a2, b2, p, false);
    }
#else
    #pragma unroll
    for (int j = 0; j < 8; ++j)
        p = fmaf((float)a[j], (float)b[j], p);
#endif
    p += __shfl_down(p, 4, 8);
    p += __shfl_down(p, 2, 8);
    p += __shfl_down(p, 1, 8);
    if (g == 0) out[e] = p;
}

extern "C" void kernel_launch(void* const* d_in, const int* in_sizes, int n_in,
                              void* d_out, int out_size, void* d_ws, size_t ws_size,
                              hipStream_t stream)
{
    const float* x   = (const float*)d_in[0];   // [N, 128]
    const int*   ei  = (const int*)  d_in[1];   // [2, E]
    const float* W1l = (const float*)d_in[2];   // [128, 64]
    const float* b1  = (const float*)d_in[3];   // [64]
    const float* W1r = (const float*)d_in[4];   // [128, 64]
    const float* W2l = (const float*)d_in[5];   // [64, 64]
    const float* b2  = (const float*)d_in[6];   // [64]
    const float* W2r = (const float*)d_in[7];   // [64, 64]
    float* out = (float*)d_out;

    const int N = in_sizes[0] / 128;            // 50000
    const int E = in_sizes[1] / 2;              // 800000
    const int* src = ei;
    const int* dst = ei + E;

    const size_t N64 = (size_t)N * 64;
    _Float16* tmp  = (_Float16*)d_ws;           // [N,64]  x@W1l (layer-1 msgs)
    _Float16* h    = tmp + N64;                 // [N,64]  x@W1r (right term)
    _Float16* z    = h + N64;                   // [N,64]  layer-2 output
    _Float16* msg2 = z + N64;                   // [N,64]  h@W2l (layer-2 msgs)
    int* deg    = (int*)(msg2 + N64);           // [N]
    int* offs   = deg + N;                      // [N]
    int* cursor = offs + N;                     // [N]
    int* csr    = cursor + N;                   // [E]
    int* bsum   = csr + E;                      // [ceil(N/256)]

    constexpr int R = 2;                        // row-iters per lane
    constexpr int EPT = 2;                      // edges per thread (placement)
    const int rows_per_block = 8 * 4 * R;       // 64
    const int nb          = (N + THREADS - 1) / THREADS;
    const int edge_blocks = (E + THREADS - 1) / THREADS;
    const int gemm_rows_blocks = (N + rows_per_block - 1) / rows_per_block; // 782
    const int edge_cover_blocks = (E + GTHREADS * EPT - 1) / (GTHREADS * EPT);
    const int gemm_blocks = gemm_rows_blocks > edge_cover_blocks
                          ? gemm_rows_blocks : edge_cover_blocks;           // 782
    const int aggm_blocks = (N + 31) / 32;                     // 1563
    const int aggr_blocks = (N + 3) / 4;
    const int scor_blocks = (E * 8 + THREADS - 1) / THREADS;

    // ---- CSR prefix (histogram + scan) ----
    hipMemsetAsync(deg, 0, (size_t)N * sizeof(int), stream);
    hist_kernel<<<edge_blocks, THREADS, 0, stream>>>(dst, deg, E);
    scan_reduce<<<nb, THREADS, 0, stream>>>(deg, bsum, N);
    scan_apply<<<nb, THREADS, 0, stream>>>(deg, bsum, offs, cursor, N);

    // ---- layer 1 GEMM with placement interleaved ----
    gemm_place<float, 128, R, EPT><<<gemm_blocks, GTHREADS, 0, stream>>>(
        x, W1l, W1r, tmp, h, N, src, dst, cursor, csr, E);

    // ---- aggregate1 + combine1 + GEMM2 fused (h stays on-chip) ----
    agg_gemm<<<aggm_blocks, THREADS, 0, stream>>>(
        tmp, csr, offs, deg, h, b1, W2l, W2r, msg2, z, N);

    // ---- layer 2 aggregate + combine ----
    aggregate_fused<<<aggr_blocks, THREADS, 0, stream>>>(msg2, csr, offs, deg, z, b2, z, N, 0);

    // ---- decode ----
    score_kernel<<<scor_blocks, THREADS, 0, stream>>>(z, src, dst, out, E);
}